// Round 5
// baseline (136.122 us; speedup 1.0000x reference)
//
#include <hip/hip_runtime.h>
#include <hip/hip_bf16.h>
#include <math.h>

#define EMB 768
#define NB 2
#define NWIN 512
#define NROWS (NB*NWIN)          // 1024
#define SWIN 64
#define HRDIM 32
#define ROWF (NROWS*EMB)         // 786432
#define WELEM (EMB*EMB)          // 589824

using bfrag = __attribute__((ext_vector_type(8))) short;   // 8 bf16 (4 VGPRs)
using f32x4 = __attribute__((ext_vector_type(4))) float;

#define GL16(g, l)  __builtin_amdgcn_global_load_lds(                         \
    (const __attribute__((address_space(1))) void*)(g),                       \
    (__attribute__((address_space(3))) void*)(l), 16, 0, 0)

// ---------------------------------------------------------------------------
// batched fp32 -> bf16 convert: 3 tensors in one launch (blockIdx.y selects)
// ---------------------------------------------------------------------------
__global__ __launch_bounds__(256)
void f2b3_kernel(const float* __restrict__ iA, __hip_bfloat16* __restrict__ oA, int nA,
                 const float* __restrict__ iB, __hip_bfloat16* __restrict__ oB, int nB,
                 const float* __restrict__ iC, __hip_bfloat16* __restrict__ oC, int nC) {
  const float* in; __hip_bfloat16* out; int n8;
  if (blockIdx.y == 0)      { in = iA; out = oA; n8 = nA; }
  else if (blockIdx.y == 1) { in = iB; out = oB; n8 = nB; }
  else                      { in = iC; out = oC; n8 = nC; }
  int i = blockIdx.x * 256 + threadIdx.x;
  if (i >= n8) return;
  float4 a = *(const float4*)&in[(size_t)i * 8];
  float4 b = *(const float4*)&in[(size_t)i * 8 + 4];
  __hip_bfloat16 t[8];
  t[0] = __float2bfloat16(a.x); t[1] = __float2bfloat16(a.y);
  t[2] = __float2bfloat16(a.z); t[3] = __float2bfloat16(a.w);
  t[4] = __float2bfloat16(b.x); t[5] = __float2bfloat16(b.y);
  t[6] = __float2bfloat16(b.z); t[7] = __float2bfloat16(b.w);
  *(uint4*)&out[(size_t)i * 8] = *(const uint4*)t;
}

// ---------------------------------------------------------------------------
// batched fp32 [768][768] -> bf16 transposed (3 weights, blockIdx.z selects)
// ---------------------------------------------------------------------------
__global__ __launch_bounds__(256)
void f2bT3_kernel(const float* __restrict__ iA, __hip_bfloat16* __restrict__ oA,
                  const float* __restrict__ iB, __hip_bfloat16* __restrict__ oB,
                  const float* __restrict__ iC, __hip_bfloat16* __restrict__ oC) {
  const float* in; __hip_bfloat16* out;
  if (blockIdx.z == 0)      { in = iA; out = oA; }
  else if (blockIdx.z == 1) { in = iB; out = oB; }
  else                      { in = iC; out = oC; }
  __shared__ float tile[32][33];
  const int bi = blockIdx.x, bj = blockIdx.y;
  const int c = threadIdx.x & 31, r8 = threadIdx.x >> 5;
#pragma unroll
  for (int rr = 0; rr < 4; ++rr) {
    int r = r8 + rr * 8;
    tile[c][r] = in[(size_t)(bi * 32 + r) * EMB + bj * 32 + c];
  }
  __syncthreads();
#pragma unroll
  for (int rr = 0; rr < 4; ++rr) {
    int n = r8 + rr * 8;
    out[(size_t)(bj * 32 + n) * EMB + bi * 32 + c] = __float2bfloat16(tile[n][c]);
  }
}

// ---------------------------------------------------------------------------
// folded biases (f32, exact):
//   bqk[j] = sum_c bq[c]*Wk[c][j]
//   bvo[p] = bo[p] + sum_n Wo[p][n]*bv[n]
// grid(6): blocks 0..2 -> bqk, 3..5 -> bvo
// ---------------------------------------------------------------------------
__global__ __launch_bounds__(256)
void bias_kernel(const float* __restrict__ bq, const float* __restrict__ Wk,
                 const float* __restrict__ Wo, const float* __restrict__ bv,
                 const float* __restrict__ bo, float* __restrict__ bqk,
                 float* __restrict__ bvo) {
  int i = blockIdx.x * 256 + threadIdx.x;
  if (i < EMB) {
    float s = 0.f;
#pragma unroll 4
    for (int c = 0; c < EMB; ++c) s = fmaf(bq[c], Wk[(size_t)c * EMB + i], s);
    bqk[i] = s;
  } else {
    int p = i - EMB;
    float s = bo[p];
#pragma unroll 4
    for (int n = 0; n < EMB; ++n) s = fmaf(Wo[(size_t)p * EMB + n], bv[n], s);
    bvo[p] = s;
  }
}

// ---------------------------------------------------------------------------
// MFMA bf16 GEMM, z-batched: C[m][n] = sum_k A[m][k] * Bm[n][k] (+ bias[n])
// blockIdx.z selects operand set {A,Bm,bias,out}. 64x64 tile, BK=64, 4 waves,
// 3-deep LDS ring via global_load_lds(16B) + counted vmcnt + raw s_barrier.
// K fixed at 768 (NT=12, fully unrolled). XOR chunk swizzle via pre-swizzled
// global source (linear LDS dest).
// ---------------------------------------------------------------------------
template<bool BIAS, bool WF32, bool WB16>
__global__ __launch_bounds__(256)
void gemm_bf16(const __hip_bfloat16* __restrict__ A0,
               const __hip_bfloat16* __restrict__ A1,
               const __hip_bfloat16* __restrict__ B0,
               const __hip_bfloat16* __restrict__ B1,
               const float* __restrict__ bias0, const float* __restrict__ bias1,
               float* __restrict__ Cf0, float* __restrict__ Cf1,
               __hip_bfloat16* __restrict__ Cb0, __hip_bfloat16* __restrict__ Cb1,
               int N) {
  constexpr int K = EMB;
  constexpr int NT = K / 64;          // 12
  const int zi = blockIdx.z;
  const __hip_bfloat16* A  = zi ? A1 : A0;
  const __hip_bfloat16* Bm = zi ? B1 : B0;
  const float* bias = zi ? bias1 : bias0;
  float* Cf = zi ? Cf1 : Cf0;
  __hip_bfloat16* Cb = zi ? Cb1 : Cb0;

  __shared__ short lsA[3][64 * 64];   // 3 x 8 KB ring
  __shared__ short lsB[3][64 * 64];
  const int t = threadIdx.x;
  const int w = t >> 6, lane = t & 63;
  const int lr = lane & 15, lk = lane >> 4;
  const int m0 = blockIdx.y * 64, n0 = blockIdx.x * 64;

  const int r0 = t >> 3, c0 = t & 7;
  const int kc = c0 ^ (r0 & 7);
  const __hip_bfloat16* aptr0 = A + (size_t)(m0 + r0) * K + kc * 8;
  const __hip_bfloat16* aptr1 = A + (size_t)(m0 + r0 + 32) * K + kc * 8;
  const __hip_bfloat16* bptr0 = Bm + (size_t)(n0 + r0) * K + kc * 8;
  const __hip_bfloat16* bptr1 = Bm + (size_t)(n0 + r0 + 32) * K + kc * 8;
  const int wbase = w * 512;

  const int arow = w * 16 + lr;
  int aoff[2], boff[4][2];
#pragma unroll
  for (int ks = 0; ks < 2; ++ks)
    aoff[ks] = arow * 64 + (((ks << 2) | lk) ^ (arow & 7)) * 8;
#pragma unroll
  for (int f = 0; f < 4; ++f) {
    int br = f * 16 + lr;
#pragma unroll
    for (int ks = 0; ks < 2; ++ks)
      boff[f][ks] = br * 64 + (((ks << 2) | lk) ^ (br & 7)) * 8;
  }

  f32x4 acc[4];
#pragma unroll
  for (int f = 0; f < 4; ++f) acc[f] = (f32x4){0.f, 0.f, 0.f, 0.f};

#pragma unroll
  for (int p = 0; p < 2; ++p) {
    int ko = p * 64;
    GL16(aptr0 + ko, &lsA[p][wbase]);
    GL16(aptr1 + ko, &lsA[p][wbase + 2048]);
    GL16(bptr0 + ko, &lsB[p][wbase]);
    GL16(bptr1 + ko, &lsB[p][wbase + 2048]);
  }

#pragma unroll
  for (int kt = 0; kt < NT; ++kt) {
    if (kt + 2 < NT) {
      constexpr int s3[NT + 2] = {0,1,2,0,1,2,0,1,2,0,1,2,0,1};
      const int sl = s3[kt + 2];
      int ko = (kt + 2) * 64;
      GL16(aptr0 + ko, &lsA[sl][wbase]);
      GL16(aptr1 + ko, &lsA[sl][wbase + 2048]);
      GL16(bptr0 + ko, &lsB[sl][wbase]);
      GL16(bptr1 + ko, &lsB[sl][wbase + 2048]);
    }
    if (kt + 2 < NT)      asm volatile("s_waitcnt vmcnt(8)" ::: "memory");
    else if (kt + 1 < NT) asm volatile("s_waitcnt vmcnt(4)" ::: "memory");
    else                  asm volatile("s_waitcnt vmcnt(0)" ::: "memory");
    __builtin_amdgcn_sched_barrier(0);
    __builtin_amdgcn_s_barrier();

    const int cur = kt % 3;
    bfrag a0 = *(const bfrag*)&lsA[cur][aoff[0]];
    bfrag a1 = *(const bfrag*)&lsA[cur][aoff[1]];
    bfrag b00 = *(const bfrag*)&lsB[cur][boff[0][0]];
    bfrag b01 = *(const bfrag*)&lsB[cur][boff[0][1]];
    bfrag b10 = *(const bfrag*)&lsB[cur][boff[1][0]];
    bfrag b11 = *(const bfrag*)&lsB[cur][boff[1][1]];
    bfrag b20 = *(const bfrag*)&lsB[cur][boff[2][0]];
    bfrag b21 = *(const bfrag*)&lsB[cur][boff[2][1]];
    bfrag b30 = *(const bfrag*)&lsB[cur][boff[3][0]];
    bfrag b31 = *(const bfrag*)&lsB[cur][boff[3][1]];
    acc[0] = __builtin_amdgcn_mfma_f32_16x16x32_bf16(a0, b00, acc[0], 0, 0, 0);
    acc[0] = __builtin_amdgcn_mfma_f32_16x16x32_bf16(a1, b01, acc[0], 0, 0, 0);
    acc[1] = __builtin_amdgcn_mfma_f32_16x16x32_bf16(a0, b10, acc[1], 0, 0, 0);
    acc[1] = __builtin_amdgcn_mfma_f32_16x16x32_bf16(a1, b11, acc[1], 0, 0, 0);
    acc[2] = __builtin_amdgcn_mfma_f32_16x16x32_bf16(a0, b20, acc[2], 0, 0, 0);
    acc[2] = __builtin_amdgcn_mfma_f32_16x16x32_bf16(a1, b21, acc[2], 0, 0, 0);
    acc[3] = __builtin_amdgcn_mfma_f32_16x16x32_bf16(a0, b30, acc[3], 0, 0, 0);
    acc[3] = __builtin_amdgcn_mfma_f32_16x16x32_bf16(a1, b31, acc[3], 0, 0, 0);

    asm volatile("s_waitcnt lgkmcnt(0)" ::: "memory");
    __builtin_amdgcn_s_barrier();
    __builtin_amdgcn_sched_barrier(0);
  }

  float bs[4] = {0.f, 0.f, 0.f, 0.f};
  if (BIAS) {
#pragma unroll
    for (int f = 0; f < 4; ++f) bs[f] = bias[n0 + f * 16 + lr];
  }
#pragma unroll
  for (int f = 0; f < 4; ++f) {
    int n = n0 + f * 16 + lr;
#pragma unroll
    for (int j = 0; j < 4; ++j) {
      int m = m0 + w * 16 + lk * 4 + j;
      float v = acc[f][j] + bs[f];
      if (WF32) Cf[(size_t)m * N + n] = v;
      if (WB16) Cb[(size_t)m * N + n] = __float2bfloat16(v);
    }
  }
}

// ---------------------------------------------------------------------------
// Attention core, online softmax, single HBM pass over HR, no window buffer.
// 8 waves x 8 rows each; per-row: load -> dot -> wave-reduce -> flash-rescale
// f32 accumulate (z in registers, 12 f32/lane). Cross-wave combine via 24 KB
// LDS partials. ~25 KB LDS, ~80 VGPR -> 3 blocks/CU (load/compute overlap).
// ---------------------------------------------------------------------------
__global__ __launch_bounds__(512)
void attn_kernel(const float* __restrict__ HR, const float* __restrict__ qt,
                 __hip_bfloat16* __restrict__ zb) {
  const int g = blockIdx.x;
  const int b = g >> 9;
  const int n = g & 511;
  const int db = n >> 6, wb = (n >> 3) & 7, hb = n & 7;

  __shared__ float zp[8][EMB];      // per-wave z partials (24 KB)
  __shared__ float ml[8][2];        // per-wave running (m, l)

  const int t = threadIdx.x;
  const int w = t >> 6, lane = t & 63;

  // query fragment: cols (lane + r*64)*4 .. +3
  float4 qv[3];
#pragma unroll
  for (int r = 0; r < 3; ++r)
    qv[r] = *(const float4*)&qt[(size_t)g * EMB + (lane + r * 64) * 4];

  // row base offsets for this wave's 8 rows (wave-uniform scalar math)
  const float* rows[8];
#pragma unroll
  for (int i = 0; i < 8; ++i) {
    int s = w * 8 + i;
    int D = db * 4 + (s >> 4), W = wb * 4 + ((s >> 2) & 3), H = hb * 4 + (s & 3);
    rows[i] = HR + (size_t)((((b * HRDIM + D) * HRDIM + W) * HRDIM + H)) * EMB;
  }

  const float scale = 0.036084391824351615f;  // 1/sqrt(768)
  float m = -3.0e38f, l = 0.f;
  float4 z0 = {0,0,0,0}, z1 = {0,0,0,0}, z2 = {0,0,0,0};

  // prefetch row 0
  float4 h0 = *(const float4*)&rows[0][lane * 4];
  float4 h1 = *(const float4*)&rows[0][(lane + 64) * 4];
  float4 h2 = *(const float4*)&rows[0][(lane + 128) * 4];

#pragma unroll
  for (int i = 0; i < 8; ++i) {
    float4 n0, n1, n2;
    if (i < 7) {
      n0 = *(const float4*)&rows[i + 1][lane * 4];
      n1 = *(const float4*)&rows[i + 1][(lane + 64) * 4];
      n2 = *(const float4*)&rows[i + 1][(lane + 128) * 4];
    }
    float p = 0.f;
    p = fmaf(h0.x, qv[0].x, p); p = fmaf(h0.y, qv[0].y, p);
    p = fmaf(h0.z, qv[0].z, p); p = fmaf(h0.w, qv[0].w, p);
    p = fmaf(h1.x, qv[1].x, p); p = fmaf(h1.y, qv[1].y, p);
    p = fmaf(h1.z, qv[1].z, p); p = fmaf(h1.w, qv[1].w, p);
    p = fmaf(h2.x, qv[2].x, p); p = fmaf(h2.y, qv[2].y, p);
    p = fmaf(h2.z, qv[2].z, p); p = fmaf(h2.w, qv[2].w, p);
#pragma unroll
    for (int o = 32; o > 0; o >>= 1) p += __shfl_xor(p, o, 64);
    p *= scale;
    float mn = fmaxf(m, p);
    float f = expf(m - mn);         // 0 on first iter (m = -3e38)
    float e = expf(p - mn);
    z0.x = fmaf(e, h0.x, z0.x * f); z0.y = fmaf(e, h0.y, z0.y * f);
    z0.z = fmaf(e, h0.z, z0.z * f); z0.w = fmaf(e, h0.w, z0.w * f);
    z1.x = fmaf(e, h1.x, z1.x * f); z1.y = fmaf(e, h1.y, z1.y * f);
    z1.z = fmaf(e, h1.z, z1.z * f); z1.w = fmaf(e, h1.w, z1.w * f);
    z2.x = fmaf(e, h2.x, z2.x * f); z2.y = fmaf(e, h2.y, z2.y * f);
    z2.z = fmaf(e, h2.z, z2.z * f); z2.w = fmaf(e, h2.w, z2.w * f);
    l = fmaf(l, f, e);
    m = mn;
    if (i < 7) { h0 = n0; h1 = n1; h2 = n2; }
  }

  *(float4*)&zp[w][lane * 4] = z0;
  *(float4*)&zp[w][(lane + 64) * 4] = z1;
  *(float4*)&zp[w][(lane + 128) * 4] = z2;
  if (lane == 0) { ml[w][0] = m; ml[w][1] = l; }
  __syncthreads();

  // combine: threads 0..383, 2 cols each
  if (t < 384) {
    float M = -3.0e38f;
#pragma unroll
    for (int w8 = 0; w8 < 8; ++w8) M = fmaxf(M, ml[w8][0]);
    float L = 0.f, a0 = 0.f, a1 = 0.f;
#pragma unroll
    for (int w8 = 0; w8 < 8; ++w8) {
      float ew = expf(ml[w8][0] - M);
      L = fmaf(ml[w8][1], ew, L);
      float2 v = *(const float2*)&zp[w8][t * 2];
      a0 = fmaf(v.x, ew, a0);
      a1 = fmaf(v.y, ew, a1);
    }
    float rl = 1.f / L;
    __hip_bfloat16 o[2];
    o[0] = __float2bfloat16(a0 * rl);
    o[1] = __float2bfloat16(a1 * rl);
    *(unsigned*)&zb[(size_t)g * EMB + t * 2] = *(const unsigned*)o;
  }
}

// ---------------------------------------------------------------------------
// res = Q + X ; out = LayerNorm(res) * g + b
// ---------------------------------------------------------------------------
__global__ __launch_bounds__(256)
void resid_ln_kernel(const float* __restrict__ Q, const float* __restrict__ X,
                     const float* __restrict__ gma, const float* __restrict__ bta,
                     float* __restrict__ out) {
  const int row = blockIdx.x;
  const int t = threadIdx.x;
  const int wave = t >> 6, lane = t & 63;
  __shared__ float red[4];

  float v[3];
  float s = 0.f;
#pragma unroll
  for (int r = 0; r < 3; ++r) {
    int c = t + r * 256;
    v[r] = Q[(size_t)row * EMB + c] + X[(size_t)row * EMB + c];
    s += v[r];
  }
#pragma unroll
  for (int o = 32; o > 0; o >>= 1) s += __shfl_xor(s, o, 64);
  if (lane == 0) red[wave] = s;
  __syncthreads();
  float mu = (red[0] + red[1] + red[2] + red[3]) * (1.f / EMB);
  __syncthreads();

  float q = 0.f;
#pragma unroll
  for (int r = 0; r < 3; ++r) {
    float d = v[r] - mu;
    q += d * d;
  }
#pragma unroll
  for (int o = 32; o > 0; o >>= 1) q += __shfl_xor(q, o, 64);
  if (lane == 0) red[wave] = q;
  __syncthreads();
  float var = (red[0] + red[1] + red[2] + red[3]) * (1.f / EMB);
  float inv = rsqrtf(var + 1e-5f);

#pragma unroll
  for (int r = 0; r < 3; ++r) {
    int c = t + r * 256;
    out[(size_t)row * EMB + c] = (v[r] - mu) * inv * gma[c] + bta[c];
  }
}

// ---------------------------------------------------------------------------
extern "C" void kernel_launch(void* const* d_in, const int* in_sizes, int n_in,
                              void* d_out, int out_size, void* d_ws, size_t ws_size,
                              hipStream_t stream) {
  const float* LR  = (const float*)d_in[0];
  const float* HR  = (const float*)d_in[1];
  const float* Wq  = (const float*)d_in[2];
  const float* bq  = (const float*)d_in[3];
  const float* Wk  = (const float*)d_in[4];
  // d_in[5] = Wk_b: softmax-invariant constant -> dropped (exact)
  const float* Wv  = (const float*)d_in[6];
  const float* bv  = (const float*)d_in[7];
  const float* Wo  = (const float*)d_in[8];
  const float* bo  = (const float*)d_in[9];
  const float* lng = (const float*)d_in[10];
  const float* lnb = (const float*)d_in[11];
  float* out = (float*)d_out;

  char* ws = (char*)d_ws;
  float* Qf = (float*)(ws + 0);                        // [1024][768] f32
  float* qt = (float*)(ws + 3145728);                  // [1024][768] f32
  float* x  = (float*)(ws + 6291456);                  // [1024][768] f32
  __hip_bfloat16* LRb  = (__hip_bfloat16*)(ws +  9437184);
  __hip_bfloat16* zb   = (__hip_bfloat16*)(ws + 11010048);
  __hip_bfloat16* Wqb  = (__hip_bfloat16*)(ws + 12582912);
  __hip_bfloat16* Wob  = (__hip_bfloat16*)(ws + 13762560);
  __hip_bfloat16* WqTb = (__hip_bfloat16*)(ws + 14942208);
  __hip_bfloat16* WkTb = (__hip_bfloat16*)(ws + 16121856);
  __hip_bfloat16* WvTb = (__hip_bfloat16*)(ws + 17301504);
  __hip_bfloat16* Wqkb = (__hip_bfloat16*)(ws + 18481152);
  __hip_bfloat16* Wvob = (__hip_bfloat16*)(ws + 19660800);
  float* bqk = (float*)(ws + 20840448);                // [768] f32
  float* bvo = (float*)(ws + 20843520);                // [768] f32

  dim3 blk(256);

  // 1) direct converts: LR, Wq, Wo
  f2b3_kernel<<<dim3(384, 3), blk, 0, stream>>>(
      LR, LRb, ROWF / 8, Wq, Wqb, WELEM / 8, Wo, Wob, WELEM / 8);
  // 2) transposed converts: WqT, WkT, WvT
  f2bT3_kernel<<<dim3(24, 24, 3), blk, 0, stream>>>(
      Wq, WqTb, Wk, WkTb, Wv, WvTb);
  // 3) folded weights: Wqk = WkT (x) WqT^T ; Wvo = Wo (x) WvT^T  (bf16 out)
  gemm_bf16<false, false, true><<<dim3(12, 12, 2), blk, 0, stream>>>(
      WkTb, Wob, WqTb, WvTb, nullptr, nullptr,
      nullptr, nullptr, Wqkb, Wvob, EMB);
  // 4) folded biases (f32, exact)
  bias_kernel<<<dim3(6), blk, 0, stream>>>(bq, Wk, Wo, bv, bo, bqk, bvo);
  // 5) Q = LR(x)Wq^T + bq  AND  qt = LR(x)Wqk^T + bqk  (batched, f32 out)
  gemm_bf16<true, true, false><<<dim3(12, 16, 2), blk, 0, stream>>>(
      LRb, LRb, Wqb, Wqkb, bq, bqk, Qf, qt, nullptr, nullptr, EMB);
  // 6) z = softmax(scale * qt . HR) @ HR   (online, HR read once; bf16 out)
  attn_kernel<<<dim3(NROWS), dim3(512), 0, stream>>>(HR, qt, zb);
  // 7) x = z(x)Wvo^T + bvo   (f32 out)
  gemm_bf16<true, true, false><<<dim3(12, 16, 1), blk, 0, stream>>>(
      zb, zb, Wvob, Wvob, bvo, bvo, x, x, nullptr, nullptr, EMB);
  // 8) out = LN(Q + x) * g + b
  resid_ln_kernel<<<dim3(NROWS), blk, 0, stream>>>(Qf, x, lng, lnb, out);
}

// Round 6
// 85.041 us; speedup vs baseline: 1.6007x; 1.6007x over previous
//
#include <hip/hip_runtime.h>
#include <hip/hip_bf16.h>
#include <math.h>

#define EMB 768
#define NB 2
#define NWIN 512
#define NROWS (NB*NWIN)          // 1024
#define SWIN 64
#define HRDIM 32
#define ROWF (NROWS*EMB)         // 786432
#define WELEM (EMB*EMB)          // 589824

using bfrag = __attribute__((ext_vector_type(8))) short;   // 8 bf16 (4 VGPRs)
using f32x4 = __attribute__((ext_vector_type(4))) float;

#define GL16(g, l)  __builtin_amdgcn_global_load_lds(                         \
    (const __attribute__((address_space(1))) void*)(g),                       \
    (__attribute__((address_space(3))) void*)(l), 16, 0, 0)

// ---------------------------------------------------------------------------
// batched fp32 -> bf16 convert: 3 tensors in one launch (blockIdx.y selects)
// ---------------------------------------------------------------------------
__global__ __launch_bounds__(256)
void f2b3_kernel(const float* __restrict__ iA, __hip_bfloat16* __restrict__ oA, int nA,
                 const float* __restrict__ iB, __hip_bfloat16* __restrict__ oB, int nB,
                 const float* __restrict__ iC, __hip_bfloat16* __restrict__ oC, int nC) {
  const float* in; __hip_bfloat16* out; int n8;
  if (blockIdx.y == 0)      { in = iA; out = oA; n8 = nA; }
  else if (blockIdx.y == 1) { in = iB; out = oB; n8 = nB; }
  else                      { in = iC; out = oC; n8 = nC; }
  int i = blockIdx.x * 256 + threadIdx.x;
  if (i >= n8) return;
  float4 a = *(const float4*)&in[(size_t)i * 8];
  float4 b = *(const float4*)&in[(size_t)i * 8 + 4];
  __hip_bfloat16 t[8];
  t[0] = __float2bfloat16(a.x); t[1] = __float2bfloat16(a.y);
  t[2] = __float2bfloat16(a.z); t[3] = __float2bfloat16(a.w);
  t[4] = __float2bfloat16(b.x); t[5] = __float2bfloat16(b.y);
  t[6] = __float2bfloat16(b.z); t[7] = __float2bfloat16(b.w);
  *(uint4*)&out[(size_t)i * 8] = *(const uint4*)t;
}

// ---------------------------------------------------------------------------
// batched fp32 [768][768] -> bf16 transposed (3 weights, blockIdx.z selects)
// ---------------------------------------------------------------------------
__global__ __launch_bounds__(256)
void f2bT3_kernel(const float* __restrict__ iA, __hip_bfloat16* __restrict__ oA,
                  const float* __restrict__ iB, __hip_bfloat16* __restrict__ oB,
                  const float* __restrict__ iC, __hip_bfloat16* __restrict__ oC) {
  const float* in; __hip_bfloat16* out;
  if (blockIdx.z == 0)      { in = iA; out = oA; }
  else if (blockIdx.z == 1) { in = iB; out = oB; }
  else                      { in = iC; out = oC; }
  __shared__ float tile[32][33];
  const int bi = blockIdx.x, bj = blockIdx.y;
  const int c = threadIdx.x & 31, r8 = threadIdx.x >> 5;
#pragma unroll
  for (int rr = 0; rr < 4; ++rr) {
    int r = r8 + rr * 8;
    tile[c][r] = in[(size_t)(bi * 32 + r) * EMB + bj * 32 + c];
  }
  __syncthreads();
#pragma unroll
  for (int rr = 0; rr < 4; ++rr) {
    int n = r8 + rr * 8;
    out[(size_t)(bj * 32 + n) * EMB + bi * 32 + c] = __float2bfloat16(tile[n][c]);
  }
}

// ---------------------------------------------------------------------------
// folded biases (f32, exact), PARALLEL version:
//   bqk[j] = sum_c bq[c]*Wk[c][j]          (column access)
//   bvo[p] = bo[p] + sum_n Wo[p][n]*bv[n]  (row access)
// blocks 0..11:   bqk, 64 outputs/block; threads = (c-group 0..3) x (out 0..63)
//                 -> coalesced 64-wide column loads, 192 iters, LDS combine.
// blocks 12..203: bvo, wave-per-output; lanes stride the row (coalesced),
//                 shuffle reduce.
// ---------------------------------------------------------------------------
__global__ __launch_bounds__(256)
void bias_kernel(const float* __restrict__ bq, const float* __restrict__ Wk,
                 const float* __restrict__ Wo, const float* __restrict__ bv,
                 const float* __restrict__ bo, float* __restrict__ bqk,
                 float* __restrict__ bvo) {
  const int t = threadIdx.x;
  if (blockIdx.x < 12) {
    __shared__ float red[4][64];
    const int io = t & 63, cg = t >> 6;
    const int i = blockIdx.x * 64 + io;
    float s = 0.f;
#pragma unroll 8
    for (int c = cg; c < EMB; c += 4)
      s = fmaf(bq[c], Wk[(size_t)c * EMB + i], s);
    red[cg][io] = s;
    __syncthreads();
    if (cg == 0)
      bqk[i] = red[0][io] + red[1][io] + red[2][io] + red[3][io];
  } else {
    const int w = t >> 6, lane = t & 63;
    const int p = (blockIdx.x - 12) * 4 + w;
    float s = 0.f;
#pragma unroll
    for (int r = 0; r < 12; ++r) {
      int n = lane + r * 64;
      s = fmaf(Wo[(size_t)p * EMB + n], bv[n], s);
    }
#pragma unroll
    for (int o = 32; o > 0; o >>= 1) s += __shfl_xor(s, o, 64);
    if (lane == 0) bvo[p] = bo[p] + s;
  }
}

// ---------------------------------------------------------------------------
// MFMA bf16 GEMM, z-batched: C[m][n] = sum_k A[m][k] * Bm[n][k] (+ bias[n])
// blockIdx.z selects operand set {A,Bm,bias,out}. 64x64 tile, BK=64, 4 waves,
// 3-deep LDS ring via global_load_lds(16B) + counted vmcnt + raw s_barrier.
// K fixed at 768 (NT=12, fully unrolled). XOR chunk swizzle via pre-swizzled
// global source (linear LDS dest).
// ---------------------------------------------------------------------------
template<bool BIAS, bool WF32, bool WB16>
__global__ __launch_bounds__(256)
void gemm_bf16(const __hip_bfloat16* __restrict__ A0,
               const __hip_bfloat16* __restrict__ A1,
               const __hip_bfloat16* __restrict__ B0,
               const __hip_bfloat16* __restrict__ B1,
               const float* __restrict__ bias0, const float* __restrict__ bias1,
               float* __restrict__ Cf0, float* __restrict__ Cf1,
               __hip_bfloat16* __restrict__ Cb0, __hip_bfloat16* __restrict__ Cb1,
               int N) {
  constexpr int K = EMB;
  constexpr int NT = K / 64;          // 12
  const int zi = blockIdx.z;
  const __hip_bfloat16* A  = zi ? A1 : A0;
  const __hip_bfloat16* Bm = zi ? B1 : B0;
  const float* bias = zi ? bias1 : bias0;
  float* Cf = zi ? Cf1 : Cf0;
  __hip_bfloat16* Cb = zi ? Cb1 : Cb0;

  __shared__ short lsA[3][64 * 64];   // 3 x 8 KB ring
  __shared__ short lsB[3][64 * 64];
  const int t = threadIdx.x;
  const int w = t >> 6, lane = t & 63;
  const int lr = lane & 15, lk = lane >> 4;
  const int m0 = blockIdx.y * 64, n0 = blockIdx.x * 64;

  const int r0 = t >> 3, c0 = t & 7;
  const int kc = c0 ^ (r0 & 7);
  const __hip_bfloat16* aptr0 = A + (size_t)(m0 + r0) * K + kc * 8;
  const __hip_bfloat16* aptr1 = A + (size_t)(m0 + r0 + 32) * K + kc * 8;
  const __hip_bfloat16* bptr0 = Bm + (size_t)(n0 + r0) * K + kc * 8;
  const __hip_bfloat16* bptr1 = Bm + (size_t)(n0 + r0 + 32) * K + kc * 8;
  const int wbase = w * 512;

  const int arow = w * 16 + lr;
  int aoff[2], boff[4][2];
#pragma unroll
  for (int ks = 0; ks < 2; ++ks)
    aoff[ks] = arow * 64 + (((ks << 2) | lk) ^ (arow & 7)) * 8;
#pragma unroll
  for (int f = 0; f < 4; ++f) {
    int br = f * 16 + lr;
#pragma unroll
    for (int ks = 0; ks < 2; ++ks)
      boff[f][ks] = br * 64 + (((ks << 2) | lk) ^ (br & 7)) * 8;
  }

  f32x4 acc[4];
#pragma unroll
  for (int f = 0; f < 4; ++f) acc[f] = (f32x4){0.f, 0.f, 0.f, 0.f};

#pragma unroll
  for (int p = 0; p < 2; ++p) {
    int ko = p * 64;
    GL16(aptr0 + ko, &lsA[p][wbase]);
    GL16(aptr1 + ko, &lsA[p][wbase + 2048]);
    GL16(bptr0 + ko, &lsB[p][wbase]);
    GL16(bptr1 + ko, &lsB[p][wbase + 2048]);
  }

#pragma unroll
  for (int kt = 0; kt < NT; ++kt) {
    if (kt + 2 < NT) {
      constexpr int s3[NT + 2] = {0,1,2,0,1,2,0,1,2,0,1,2,0,1};
      const int sl = s3[kt + 2];
      int ko = (kt + 2) * 64;
      GL16(aptr0 + ko, &lsA[sl][wbase]);
      GL16(aptr1 + ko, &lsA[sl][wbase + 2048]);
      GL16(bptr0 + ko, &lsB[sl][wbase]);
      GL16(bptr1 + ko, &lsB[sl][wbase + 2048]);
    }
    if (kt + 2 < NT)      asm volatile("s_waitcnt vmcnt(8)" ::: "memory");
    else if (kt + 1 < NT) asm volatile("s_waitcnt vmcnt(4)" ::: "memory");
    else                  asm volatile("s_waitcnt vmcnt(0)" ::: "memory");
    __builtin_amdgcn_sched_barrier(0);
    __builtin_amdgcn_s_barrier();

    const int cur = kt % 3;
    bfrag a0 = *(const bfrag*)&lsA[cur][aoff[0]];
    bfrag a1 = *(const bfrag*)&lsA[cur][aoff[1]];
    bfrag b00 = *(const bfrag*)&lsB[cur][boff[0][0]];
    bfrag b01 = *(const bfrag*)&lsB[cur][boff[0][1]];
    bfrag b10 = *(const bfrag*)&lsB[cur][boff[1][0]];
    bfrag b11 = *(const bfrag*)&lsB[cur][boff[1][1]];
    bfrag b20 = *(const bfrag*)&lsB[cur][boff[2][0]];
    bfrag b21 = *(const bfrag*)&lsB[cur][boff[2][1]];
    bfrag b30 = *(const bfrag*)&lsB[cur][boff[3][0]];
    bfrag b31 = *(const bfrag*)&lsB[cur][boff[3][1]];
    acc[0] = __builtin_amdgcn_mfma_f32_16x16x32_bf16(a0, b00, acc[0], 0, 0, 0);
    acc[0] = __builtin_amdgcn_mfma_f32_16x16x32_bf16(a1, b01, acc[0], 0, 0, 0);
    acc[1] = __builtin_amdgcn_mfma_f32_16x16x32_bf16(a0, b10, acc[1], 0, 0, 0);
    acc[1] = __builtin_amdgcn_mfma_f32_16x16x32_bf16(a1, b11, acc[1], 0, 0, 0);
    acc[2] = __builtin_amdgcn_mfma_f32_16x16x32_bf16(a0, b20, acc[2], 0, 0, 0);
    acc[2] = __builtin_amdgcn_mfma_f32_16x16x32_bf16(a1, b21, acc[2], 0, 0, 0);
    acc[3] = __builtin_amdgcn_mfma_f32_16x16x32_bf16(a0, b30, acc[3], 0, 0, 0);
    acc[3] = __builtin_amdgcn_mfma_f32_16x16x32_bf16(a1, b31, acc[3], 0, 0, 0);

    asm volatile("s_waitcnt lgkmcnt(0)" ::: "memory");
    __builtin_amdgcn_s_barrier();
    __builtin_amdgcn_sched_barrier(0);
  }

  float bs[4] = {0.f, 0.f, 0.f, 0.f};
  if (BIAS) {
#pragma unroll
    for (int f = 0; f < 4; ++f) bs[f] = bias[n0 + f * 16 + lr];
  }
#pragma unroll
  for (int f = 0; f < 4; ++f) {
    int n = n0 + f * 16 + lr;
#pragma unroll
    for (int j = 0; j < 4; ++j) {
      int m = m0 + w * 16 + lk * 4 + j;
      float v = acc[f][j] + bs[f];
      if (WF32) Cf[(size_t)m * N + n] = v;
      if (WB16) Cb[(size_t)m * N + n] = __float2bfloat16(v);
    }
  }
}

// ---------------------------------------------------------------------------
// Attention core, online softmax, single HBM pass over HR, no window buffer.
// 8 waves x 8 rows each; per-row: load -> dot -> wave-reduce -> flash-rescale
// f32 accumulate (z in registers, 12 f32/lane). Cross-wave combine via 24 KB
// LDS partials. ~25 KB LDS, ~80 VGPR -> 3 blocks/CU (load/compute overlap).
// ---------------------------------------------------------------------------
__global__ __launch_bounds__(512)
void attn_kernel(const float* __restrict__ HR, const float* __restrict__ qt,
                 __hip_bfloat16* __restrict__ zb) {
  const int g = blockIdx.x;
  const int b = g >> 9;
  const int n = g & 511;
  const int db = n >> 6, wb = (n >> 3) & 7, hb = n & 7;

  __shared__ float zp[8][EMB];      // per-wave z partials (24 KB)
  __shared__ float ml[8][2];        // per-wave running (m, l)

  const int t = threadIdx.x;
  const int w = t >> 6, lane = t & 63;

  float4 qv[3];
#pragma unroll
  for (int r = 0; r < 3; ++r)
    qv[r] = *(const float4*)&qt[(size_t)g * EMB + (lane + r * 64) * 4];

  const float* rows[8];
#pragma unroll
  for (int i = 0; i < 8; ++i) {
    int s = w * 8 + i;
    int D = db * 4 + (s >> 4), W = wb * 4 + ((s >> 2) & 3), H = hb * 4 + (s & 3);
    rows[i] = HR + (size_t)((((b * HRDIM + D) * HRDIM + W) * HRDIM + H)) * EMB;
  }

  const float scale = 0.036084391824351615f;  // 1/sqrt(768)
  float m = -3.0e38f, l = 0.f;
  float4 z0 = {0,0,0,0}, z1 = {0,0,0,0}, z2 = {0,0,0,0};

  float4 h0 = *(const float4*)&rows[0][lane * 4];
  float4 h1 = *(const float4*)&rows[0][(lane + 64) * 4];
  float4 h2 = *(const float4*)&rows[0][(lane + 128) * 4];

#pragma unroll
  for (int i = 0; i < 8; ++i) {
    float4 n0, n1, n2;
    if (i < 7) {
      n0 = *(const float4*)&rows[i + 1][lane * 4];
      n1 = *(const float4*)&rows[i + 1][(lane + 64) * 4];
      n2 = *(const float4*)&rows[i + 1][(lane + 128) * 4];
    }
    float p = 0.f;
    p = fmaf(h0.x, qv[0].x, p); p = fmaf(h0.y, qv[0].y, p);
    p = fmaf(h0.z, qv[0].z, p); p = fmaf(h0.w, qv[0].w, p);
    p = fmaf(h1.x, qv[1].x, p); p = fmaf(h1.y, qv[1].y, p);
    p = fmaf(h1.z, qv[1].z, p); p = fmaf(h1.w, qv[1].w, p);
    p = fmaf(h2.x, qv[2].x, p); p = fmaf(h2.y, qv[2].y, p);
    p = fmaf(h2.z, qv[2].z, p); p = fmaf(h2.w, qv[2].w, p);
#pragma unroll
    for (int o = 32; o > 0; o >>= 1) p += __shfl_xor(p, o, 64);
    p *= scale;
    float mn = fmaxf(m, p);
    float f = expf(m - mn);         // 0 on first iter (m = -3e38)
    float e = expf(p - mn);
    z0.x = fmaf(e, h0.x, z0.x * f); z0.y = fmaf(e, h0.y, z0.y * f);
    z0.z = fmaf(e, h0.z, z0.z * f); z0.w = fmaf(e, h0.w, z0.w * f);
    z1.x = fmaf(e, h1.x, z1.x * f); z1.y = fmaf(e, h1.y, z1.y * f);
    z1.z = fmaf(e, h1.z, z1.z * f); z1.w = fmaf(e, h1.w, z1.w * f);
    z2.x = fmaf(e, h2.x, z2.x * f); z2.y = fmaf(e, h2.y, z2.y * f);
    z2.z = fmaf(e, h2.z, z2.z * f); z2.w = fmaf(e, h2.w, z2.w * f);
    l = fmaf(l, f, e);
    m = mn;
    if (i < 7) { h0 = n0; h1 = n1; h2 = n2; }
  }

  *(float4*)&zp[w][lane * 4] = z0;
  *(float4*)&zp[w][(lane + 64) * 4] = z1;
  *(float4*)&zp[w][(lane + 128) * 4] = z2;
  if (lane == 0) { ml[w][0] = m; ml[w][1] = l; }
  __syncthreads();

  if (t < 384) {
    float M = -3.0e38f;
#pragma unroll
    for (int w8 = 0; w8 < 8; ++w8) M = fmaxf(M, ml[w8][0]);
    float L = 0.f, a0 = 0.f, a1 = 0.f;
#pragma unroll
    for (int w8 = 0; w8 < 8; ++w8) {
      float ew = expf(ml[w8][0] - M);
      L = fmaf(ml[w8][1], ew, L);
      float2 v = *(const float2*)&zp[w8][t * 2];
      a0 = fmaf(v.x, ew, a0);
      a1 = fmaf(v.y, ew, a1);
    }
    float rl = 1.f / L;
    __hip_bfloat16 o[2];
    o[0] = __float2bfloat16(a0 * rl);
    o[1] = __float2bfloat16(a1 * rl);
    *(unsigned*)&zb[(size_t)g * EMB + t * 2] = *(const unsigned*)o;
  }
}

// ---------------------------------------------------------------------------
// res = Q + X ; out = LayerNorm(res) * g + b
// ---------------------------------------------------------------------------
__global__ __launch_bounds__(256)
void resid_ln_kernel(const float* __restrict__ Q, const float* __restrict__ X,
                     const float* __restrict__ gma, const float* __restrict__ bta,
                     float* __restrict__ out) {
  const int row = blockIdx.x;
  const int t = threadIdx.x;
  const int wave = t >> 6, lane = t & 63;
  __shared__ float red[4];

  float v[3];
  float s = 0.f;
#pragma unroll
  for (int r = 0; r < 3; ++r) {
    int c = t + r * 256;
    v[r] = Q[(size_t)row * EMB + c] + X[(size_t)row * EMB + c];
    s += v[r];
  }
#pragma unroll
  for (int o = 32; o > 0; o >>= 1) s += __shfl_xor(s, o, 64);
  if (lane == 0) red[wave] = s;
  __syncthreads();
  float mu = (red[0] + red[1] + red[2] + red[3]) * (1.f / EMB);
  __syncthreads();

  float q = 0.f;
#pragma unroll
  for (int r = 0; r < 3; ++r) {
    float d = v[r] - mu;
    q += d * d;
  }
#pragma unroll
  for (int o = 32; o > 0; o >>= 1) q += __shfl_xor(q, o, 64);
  if (lane == 0) red[wave] = q;
  __syncthreads();
  float var = (red[0] + red[1] + red[2] + red[3]) * (1.f / EMB);
  float inv = rsqrtf(var + 1e-5f);

#pragma unroll
  for (int r = 0; r < 3; ++r) {
    int c = t + r * 256;
    out[(size_t)row * EMB + c] = (v[r] - mu) * inv * gma[c] + bta[c];
  }
}

// ---------------------------------------------------------------------------
extern "C" void kernel_launch(void* const* d_in, const int* in_sizes, int n_in,
                              void* d_out, int out_size, void* d_ws, size_t ws_size,
                              hipStream_t stream) {
  const float* LR  = (const float*)d_in[0];
  const float* HR  = (const float*)d_in[1];
  const float* Wq  = (const float*)d_in[2];
  const float* bq  = (const float*)d_in[3];
  const float* Wk  = (const float*)d_in[4];
  // d_in[5] = Wk_b: softmax-invariant constant -> dropped (exact)
  const float* Wv  = (const float*)d_in[6];
  const float* bv  = (const float*)d_in[7];
  const float* Wo  = (const float*)d_in[8];
  const float* bo  = (const float*)d_in[9];
  const float* lng = (const float*)d_in[10];
  const float* lnb = (const float*)d_in[11];
  float* out = (float*)d_out;

  char* ws = (char*)d_ws;
  float* Qf = (float*)(ws + 0);                        // [1024][768] f32
  float* qt = (float*)(ws + 3145728);                  // [1024][768] f32
  float* x  = (float*)(ws + 6291456);                  // [1024][768] f32
  __hip_bfloat16* LRb  = (__hip_bfloat16*)(ws +  9437184);
  __hip_bfloat16* zb   = (__hip_bfloat16*)(ws + 11010048);
  __hip_bfloat16* Wqb  = (__hip_bfloat16*)(ws + 12582912);
  __hip_bfloat16* Wob  = (__hip_bfloat16*)(ws + 13762560);
  __hip_bfloat16* WqTb = (__hip_bfloat16*)(ws + 14942208);
  __hip_bfloat16* WkTb = (__hip_bfloat16*)(ws + 16121856);
  __hip_bfloat16* WvTb = (__hip_bfloat16*)(ws + 17301504);
  __hip_bfloat16* Wqkb = (__hip_bfloat16*)(ws + 18481152);
  __hip_bfloat16* Wvob = (__hip_bfloat16*)(ws + 19660800);
  float* bqk = (float*)(ws + 20840448);                // [768] f32
  float* bvo = (float*)(ws + 20843520);                // [768] f32

  dim3 blk(256);

  // 1) direct converts: LR, Wq, Wo
  f2b3_kernel<<<dim3(384, 3), blk, 0, stream>>>(
      LR, LRb, ROWF / 8, Wq, Wqb, WELEM / 8, Wo, Wob, WELEM / 8);
  // 2) transposed converts: WqT, WkT, WvT
  f2bT3_kernel<<<dim3(24, 24, 3), blk, 0, stream>>>(
      Wq, WqTb, Wk, WkTb, Wv, WvTb);
  // 3) folded weights: Wqk = WkT (x) WqT^T ; Wvo = Wo (x) WvT^T  (bf16 out)
  gemm_bf16<false, false, true><<<dim3(12, 12, 2), blk, 0, stream>>>(
      WkTb, Wob, WqTb, WvTb, nullptr, nullptr,
      nullptr, nullptr, Wqkb, Wvob, EMB);
  // 4) folded biases (f32, exact, parallel)
  bias_kernel<<<dim3(204), blk, 0, stream>>>(bq, Wk, Wo, bv, bo, bqk, bvo);
  // 5) Q = LR(x)Wq^T + bq  AND  qt = LR(x)Wqk^T + bqk  (batched, f32 out)
  gemm_bf16<true, true, false><<<dim3(12, 16, 2), blk, 0, stream>>>(
      LRb, LRb, Wqb, Wqkb, bq, bqk, Qf, qt, nullptr, nullptr, EMB);
  // 6) z = softmax(scale * qt . HR) @ HR   (online, HR read once; bf16 out)
  attn_kernel<<<dim3(NROWS), dim3(512), 0, stream>>>(HR, qt, zb);
  // 7) x = z(x)Wvo^T + bvo   (f32 out)
  gemm_bf16<true, true, false><<<dim3(12, 16, 1), blk, 0, stream>>>(
      zb, zb, Wvob, Wvob, bvo, bvo, x, x, nullptr, nullptr, EMB);
  // 8) out = LN(Q + x) * g + b
  resid_ln_kernel<<<dim3(NROWS), blk, 0, stream>>>(Qf, x, lng, lnb, out);
}